// Round 3
// baseline (1083.950 us; speedup 1.0000x reference)
//
#include <hip/hip_runtime.h>
#include <math.h>

#define BH    64
#define NSEQ  4096
#define DDIM  64
#define MDIM  266
#define MPAD  272
#define RATIO 0.06131393394849658f   // 1/sqrt(266)
#define NORMF 0.35355339059327373f   // 64^-0.25
#define DIAGF 0.0625f                // 0.5 * 64^-0.5
#define EPSF  1e-4f

typedef __attribute__((ext_vector_type(8))) short bf16x8;
typedef __attribute__((ext_vector_type(4))) float f32x4;

__device__ __forceinline__ unsigned fenc(float f) {
  unsigned u = __float_as_uint(f);
  return (u & 0x80000000u) ? ~u : (u | 0x80000000u);
}
__device__ __forceinline__ float fdec(unsigned u) {
  return (u & 0x80000000u) ? __uint_as_float(u & 0x7fffffffu) : __uint_as_float(~u);
}

// split 8 f32 into bf16 hi/lo planes (truncation; lo.lo dropped error ~2^-16 rel)
__device__ __forceinline__ void splitf(float4 a, float4 b, bf16x8& hi, bf16x8& lo) {
  float x[8] = {a.x, a.y, a.z, a.w, b.x, b.y, b.z, b.w};
#pragma unroll
  for (int e = 0; e < 8; ++e) {
    unsigned ux = __float_as_uint(x[e]);
    float hf = __uint_as_float(ux & 0xffff0000u);
    hi[e] = (short)(ux >> 16);
    lo[e] = (short)(__float_as_uint(x[e] - hf) >> 16);
  }
}

// dash-GEMM accumulate: acc += bf16x3( A(16x32) * B(32x16) )
__device__ __forceinline__ f32x4 mfma3(bf16x8 ah, bf16x8 al, bf16x8 bh, bf16x8 bl, f32x4 acc) {
  acc = __builtin_amdgcn_mfma_f32_16x16x32_bf16(ah, bh, acc, 0, 0, 0);
  acc = __builtin_amdgcn_mfma_f32_16x16x32_bf16(ah, bl, acc, 0, 0, 0);
  acc = __builtin_amdgcn_mfma_f32_16x16x32_bf16(al, bh, acc, 0, 0, 0);
  return acc;
}

// ---------------------------------------------------------------------------
// P prep: proj [266][64] f32 -> phi/plo [272][64] bf16 (rows >=266 zero)
// ---------------------------------------------------------------------------
__global__ __launch_bounds__(256) void pprep_kernel(const float* __restrict__ proj,
                                                    short* __restrict__ phi,
                                                    short* __restrict__ plo) {
  int idx = blockIdx.x * 256 + threadIdx.x;
  if (idx >= MPAD * DDIM) return;
  int j = idx >> 6;
  float x = (j < MDIM) ? proj[idx] : 0.f;
  unsigned ux = __float_as_uint(x);
  float hf = __uint_as_float(ux & 0xffff0000u);
  phi[idx] = (short)(ux >> 16);
  plo[idx] = (short)(__float_as_uint(x - hf) >> 16);
}

// ---------------------------------------------------------------------------
// Kernel A: global max of k_dash = NORMF*(K.P^T), MFMA bf16x3. 64 rows/block.
// ---------------------------------------------------------------------------
__global__ __launch_bounds__(256) void kmax_kernel(const float* __restrict__ k,
                                                   const short* __restrict__ phi,
                                                   const short* __restrict__ plo,
                                                   unsigned* __restrict__ kmax) {
  __shared__ float sK[64 * 76];
  const int tid = threadIdx.x;
  const int lane = tid & 63, wv = tid >> 6, lrow = lane & 15, lgrp = lane >> 4;
  const int bh = blockIdx.x >> 6, ch = blockIdx.x & 63;
  const float* kb = k + ((size_t)bh * NSEQ + (size_t)ch * 64) * DDIM;

#pragma unroll
  for (int t = 0; t < 4; ++t) {
    int fid = tid + t * 256, r = fid >> 4, d4 = fid & 15;
    *(float4*)&sK[r * 76 + d4 * 4] = ((const float4*)kb)[fid];
  }
  __syncthreads();

  bf16x8 ahi[2], alo[2];
#pragma unroll
  for (int s = 0; s < 2; ++s) {
    const float* p = &sK[(wv * 16 + lrow) * 76 + s * 32 + lgrp * 8];
    splitf(*(const float4*)p, *(const float4*)(p + 4), ahi[s], alo[s]);
  }

  float tmax = -1e30f;
#pragma unroll
  for (int jt = 0; jt < 17; ++jt) {
    f32x4 acc = {0.f, 0.f, 0.f, 0.f};
#pragma unroll
    for (int s = 0; s < 2; ++s) {
      const size_t bo = ((size_t)(jt * 16 + lrow)) * DDIM + s * 32 + lgrp * 8;
      acc = mfma3(ahi[s], alo[s], *(const bf16x8*)(phi + bo), *(const bf16x8*)(plo + bo), acc);
    }
    if (jt < 16 || lrow < 10) {
#pragma unroll
      for (int i = 0; i < 4; ++i) tmax = fmaxf(tmax, acc[i]);
    }
  }
  tmax *= NORMF;
#pragma unroll
  for (int off = 32; off; off >>= 1) tmax = fmaxf(tmax, __shfl_xor(tmax, off));
  if ((tid & 63) == 0) atomicMax(kmax, fenc(tmax));
}

// ---------------------------------------------------------------------------
// Kernel B: k_dash via MFMA -> exp -> k' in LDS -> VALU outer product into
// accC[5 chunks] regs -> atomicAdd. 512 rows/block, row-tile(64) outer.
// ---------------------------------------------------------------------------
__global__ __launch_bounds__(256) void ctx_kernel(const float* __restrict__ k,
                                                  const float* __restrict__ v,
                                                  const short* __restrict__ phi,
                                                  const short* __restrict__ plo,
                                                  const unsigned* __restrict__ kmaxp,
                                                  float* __restrict__ ctx,
                                                  float* __restrict__ ksum) {
  __shared__ float buf[64 * 76];   // K tile (stride 76) -> k' (stride 68)
  __shared__ float sV[64 * 68];
  __shared__ float sDiag[64];
  const int tid = threadIdx.x, tx = tid & 15, ty = tid >> 4;
  const int lane = tid & 63, wv = tid >> 6, lrow = lane & 15, lgrp = lane >> 4;
  const int bh = blockIdx.x >> 3, c8 = blockIdx.x & 7;
  const float stab = fdec(*kmaxp);
  const float* kb = k + ((size_t)bh * NSEQ + (size_t)c8 * 512) * DDIM;
  const float* vb = v + ((size_t)bh * NSEQ + (size_t)c8 * 512) * DDIM;

  float accC[5][4][4];
#pragma unroll
  for (int c = 0; c < 5; ++c)
#pragma unroll
    for (int a = 0; a < 4; ++a)
#pragma unroll
      for (int b = 0; b < 4; ++b) accC[c][a][b] = 0.f;
  float ks[5] = {0.f, 0.f, 0.f, 0.f, 0.f};

  for (int rt = 0; rt < 8; ++rt) {
    // stage K, V (prev iteration's trailing sync guarantees buf/sV free)
#pragma unroll
    for (int t = 0; t < 4; ++t) {
      int fid = tid + t * 256, r = fid >> 4, d4 = fid & 15;
      *(float4*)&buf[r * 76 + d4 * 4] = ((const float4*)(kb + (size_t)rt * 64 * DDIM))[fid];
      *(float4*)&sV[r * 68 + d4 * 4] = ((const float4*)(vb + (size_t)rt * 64 * DDIM))[fid];
    }
    __syncthreads();
    if (tid < 64) {
      float s = 0.f;
      const float* row = &buf[tid * 76];
#pragma unroll
      for (int d = 0; d < 64; d += 4) {
        float4 x = *(const float4*)(row + d);
        s = fmaf(x.x, x.x, fmaf(x.y, x.y, fmaf(x.z, x.z, fmaf(x.w, x.w, s))));
      }
      sDiag[tid] = s * DIAGF;
    }
    bf16x8 ahi[2], alo[2];
#pragma unroll
    for (int s = 0; s < 2; ++s) {
      const float* p = &buf[(wv * 16 + lrow) * 76 + s * 32 + lgrp * 8];
      splitf(*(const float4*)p, *(const float4*)(p + 4), ahi[s], alo[s]);
    }
    __syncthreads();   // sDiag visible; all A/diag reads of buf drained

#pragma unroll
    for (int c = 0; c < 5; ++c) {
      const int njt = (c < 4) ? 4 : 1;
      // k_dash tiles -> exp -> k' into buf (stride 68, own wave's 16 rows)
#pragma unroll
      for (int t = 0; t < njt; ++t) {
        const int jt = c * 4 + t;
        f32x4 acc = {0.f, 0.f, 0.f, 0.f};
#pragma unroll
        for (int s = 0; s < 2; ++s) {
          const size_t bo = ((size_t)(jt * 16 + lrow)) * DDIM + s * 32 + lgrp * 8;
          acc = mfma3(ahi[s], alo[s], *(const bf16x8*)(phi + bo), *(const bf16x8*)(plo + bo), acc);
        }
        const int jg = jt * 16 + lrow;
#pragma unroll
        for (int i = 0; i < 4; ++i) {
          const int row = wv * 16 + lgrp * 4 + i;
          float kd = acc[i] * NORMF;
          float kp = (jg < MDIM) ? RATIO * (__expf(kd - sDiag[row] - stab) + EPSF) : 0.f;
          buf[row * 68 + t * 16 + lrow] = kp;
        }
      }
      __syncthreads();   // k' chunk visible to all
      // outer product: accC[c] += k'^T V  (chunk 4: only wave 0 has real cols)
      if (c < 4 || ty < 4) {
#pragma unroll 2
        for (int r = 0; r < 64; ++r) {
          float4 kp4 = *(const float4*)&buf[r * 68 + ty * 4];
          float4 vv = *(const float4*)&sV[r * 68 + tx * 4];
#pragma unroll
          for (int b = 0; b < 4; ++b) {
            const float ve = ((const float*)&vv)[b];
            accC[c][0][b] = fmaf(kp4.x, ve, accC[c][0][b]);
            accC[c][1][b] = fmaf(kp4.y, ve, accC[c][1][b]);
            accC[c][2][b] = fmaf(kp4.z, ve, accC[c][2][b]);
            accC[c][3][b] = fmaf(kp4.w, ve, accC[c][3][b]);
          }
        }
      }
      if (tid < ((c < 4) ? 64 : 16)) {
        float s = 0.f;
        for (int r = 0; r < 64; ++r) s += buf[r * 68 + tid];
        ks[c] += s;
      }
      __syncthreads();   // outer reads done before next chunk / next rt staging
    }
  }

#pragma unroll
  for (int c = 0; c < 5; ++c) {
#pragma unroll
    for (int a = 0; a < 4; ++a) {
      const int jg = c * 64 + ty * 4 + a;
      if (jg < MDIM) {
#pragma unroll
        for (int b = 0; b < 4; ++b)
          atomicAdd(&ctx[((size_t)bh * MDIM + jg) * DDIM + tx * 4 + b], accC[c][a][b]);
      }
    }
    if (tid < 64 && c * 64 + tid < MDIM)
      atomicAdd(&ksum[(size_t)bh * MDIM + c * 64 + tid], ks[c]);
  }
}

// ---------------------------------------------------------------------------
// Kernel C: q_dash via MFMA -> row max/exp/Dinv in-register -> VALU GEMM2.
// 64 rows/block.
// ---------------------------------------------------------------------------
__global__ __launch_bounds__(256) void out_kernel(const float* __restrict__ q,
                                                  const short* __restrict__ phi,
                                                  const short* __restrict__ plo,
                                                  const float* __restrict__ ctx,
                                                  const float* __restrict__ ksum,
                                                  float* __restrict__ out) {
  __shared__ float buf[64 * 76];   // Q (stride 76) -> q'*Dinv (stride 68)
  __shared__ float sCtx[64 * 68];
  __shared__ float sDiag[64];
  __shared__ float sKs[MPAD];
  const int tid = threadIdx.x, tx = tid & 15, ty = tid >> 4;
  const int lane = tid & 63, wv = tid >> 6, lrow = lane & 15, lgrp = lane >> 4;
  const int bh = blockIdx.x >> 6, rc = blockIdx.x & 63;
  const float* qb = q + ((size_t)bh * NSEQ + (size_t)rc * 64) * DDIM;

#pragma unroll
  for (int t = 0; t < 4; ++t) {
    int fid = tid + t * 256, r = fid >> 4, d4 = fid & 15;
    *(float4*)&buf[r * 76 + d4 * 4] = ((const float4*)qb)[fid];
  }
  for (int t = tid; t < MPAD; t += 256) sKs[t] = (t < MDIM) ? ksum[(size_t)bh * MDIM + t] : 0.f;
  __syncthreads();
  if (tid < 64) {
    float s = 0.f;
    const float* row = &buf[tid * 76];
#pragma unroll
    for (int d = 0; d < 64; d += 4) {
      float4 x = *(const float4*)(row + d);
      s = fmaf(x.x, x.x, fmaf(x.y, x.y, fmaf(x.z, x.z, fmaf(x.w, x.w, s))));
    }
    sDiag[tid] = s * DIAGF;
  }
  bf16x8 ahi[2], alo[2];
#pragma unroll
  for (int s = 0; s < 2; ++s) {
    const float* p = &buf[(wv * 16 + lrow) * 76 + s * 32 + lgrp * 8];
    splitf(*(const float4*)p, *(const float4*)(p + 4), ahi[s], alo[s]);
  }
  __syncthreads();   // sDiag visible; buf reads drained (safe to overwrite later)

  // q_dash fragments for all 17 j-tiles
  f32x4 qd[17];
#pragma unroll
  for (int jt = 0; jt < 17; ++jt) {
    f32x4 acc = {0.f, 0.f, 0.f, 0.f};
#pragma unroll
    for (int s = 0; s < 2; ++s) {
      const size_t bo = ((size_t)(jt * 16 + lrow)) * DDIM + s * 32 + lgrp * 8;
      acc = mfma3(ahi[s], alo[s], *(const bf16x8*)(phi + bo), *(const bf16x8*)(plo + bo), acc);
    }
#pragma unroll
    for (int i = 0; i < 4; ++i) qd[jt][i] = acc[i] * NORMF;
  }

  // per-row max, exp, Dinv (rows = wv*16 + lgrp*4 + i; 16 lanes share a row)
  float di[4];
#pragma unroll
  for (int i = 0; i < 4; ++i) {
    float m = -1e30f;
#pragma unroll
    for (int jt = 0; jt < 17; ++jt)
      if (jt < 16 || lrow < 10) m = fmaxf(m, qd[jt][i]);
    m = fmaxf(m, __shfl_xor(m, 1));
    m = fmaxf(m, __shfl_xor(m, 2));
    m = fmaxf(m, __shfl_xor(m, 4));
    m = fmaxf(m, __shfl_xor(m, 8));
    const float dg = sDiag[wv * 16 + lgrp * 4 + i];
    float s = 0.f;
#pragma unroll
    for (int jt = 0; jt < 17; ++jt) {
      const int jg = jt * 16 + lrow;
      float val = (jg < MDIM) ? RATIO * (__expf(qd[jt][i] - dg - m) + EPSF) : 0.f;
      qd[jt][i] = val;
      s = fmaf(val, sKs[jg], s);
    }
    s += __shfl_xor(s, 1);
    s += __shfl_xor(s, 2);
    s += __shfl_xor(s, 4);
    s += __shfl_xor(s, 8);
    di[i] = 1.0f / s;
  }

  // GEMM2: out = (q'*Dinv) @ ctx, chunk at a time
  float accO[4][4];
#pragma unroll
  for (int i = 0; i < 4; ++i)
#pragma unroll
    for (int b = 0; b < 4; ++b) accO[i][b] = 0.f;

#pragma unroll
  for (int c = 0; c < 5; ++c) {
    const int jn = (c < 4) ? 64 : 10;
    const int njt = (c < 4) ? 4 : 1;
    // write q'' chunk (own wave's rows), stage ctx chunk
#pragma unroll
    for (int t = 0; t < njt; ++t) {
      const int jt = c * 4 + t;
#pragma unroll
      for (int i = 0; i < 4; ++i)
        buf[(wv * 16 + lgrp * 4 + i) * 68 + t * 16 + lrow] = qd[jt][i] * di[i];
    }
#pragma unroll
    for (int t = 0; t < 4; ++t) {
      int fid = tid + t * 256, r = fid >> 4, e4 = fid & 15;
      if (r < jn)
        *(float4*)&sCtx[r * 68 + e4 * 4] =
            ((const float4*)(ctx + ((size_t)bh * MDIM + c * 64 + r) * DDIM))[e4];
    }
    __syncthreads();

    const int jlim = (c < 4) ? 64 : 12;
#pragma unroll 2
    for (int jj = 0; jj < jlim; jj += 4) {
      float4 qv[4], cv[4];
#pragma unroll
      for (int i = 0; i < 4; ++i) qv[i] = *(const float4*)&buf[(ty * 4 + i) * 68 + jj];
#pragma unroll
      for (int u = 0; u < 4; ++u) cv[u] = *(const float4*)&sCtx[(jj + u) * 68 + tx * 4];
#pragma unroll
      for (int i = 0; i < 4; ++i)
#pragma unroll
        for (int b = 0; b < 4; ++b) {
          accO[i][b] = fmaf(qv[i].x, ((const float*)&cv[0])[b], accO[i][b]);
          accO[i][b] = fmaf(qv[i].y, ((const float*)&cv[1])[b], accO[i][b]);
          accO[i][b] = fmaf(qv[i].z, ((const float*)&cv[2])[b], accO[i][b]);
          accO[i][b] = fmaf(qv[i].w, ((const float*)&cv[3])[b], accO[i][b]);
        }
    }
    __syncthreads();   // GEMM2 reads done before next chunk overwrites buf/sCtx
  }

#pragma unroll
  for (int i = 0; i < 4; ++i) {
    const int r = ty * 4 + i;
    float4 o = make_float4(accO[i][0], accO[i][1], accO[i][2], accO[i][3]);
    *(float4*)&out[((size_t)bh * NSEQ + (size_t)rc * 64 + r) * DDIM + tx * 4] = o;
  }
}

extern "C" void kernel_launch(void* const* d_in, const int* in_sizes, int n_in,
                              void* d_out, int out_size, void* d_ws, size_t ws_size,
                              hipStream_t stream) {
  (void)in_sizes; (void)n_in; (void)out_size; (void)ws_size;
  const float* q = (const float*)d_in[0];
  const float* k = (const float*)d_in[1];
  const float* v = (const float*)d_in[2];
  const float* proj = (const float*)d_in[3];
  float* out = (float*)d_out;

  unsigned* kmax = (unsigned*)d_ws;
  float* ctx = (float*)((char*)d_ws + 256);
  float* ksum = ctx + (size_t)BH * MDIM * DDIM;
  short* phi = (short*)(ksum + (size_t)BH * MDIM);
  short* plo = phi + (size_t)MPAD * DDIM;
  const size_t zero_bytes = 256 + ((size_t)BH * MDIM * DDIM + (size_t)BH * MDIM) * 4;

  hipMemsetAsync(d_ws, 0, zero_bytes, stream);
  pprep_kernel<<<dim3((MPAD * DDIM + 255) / 256), dim3(256), 0, stream>>>(proj, phi, plo);
  kmax_kernel<<<dim3(BH * 64), dim3(256), 0, stream>>>(k, phi, plo, kmax);
  ctx_kernel<<<dim3(BH * 8), dim3(256), 0, stream>>>(k, v, phi, plo, kmax, ctx, ksum);
  out_kernel<<<dim3(BH * 64), dim3(256), 0, stream>>>(q, phi, plo, ctx, ksum, out);
}

// Round 4
// 692.101 us; speedup vs baseline: 1.5662x; 1.5662x over previous
//
#include <hip/hip_runtime.h>
#include <math.h>

#define BH    64
#define NSEQ  4096
#define DDIM  64
#define MDIM  266
#define MPAD  272
#define RATIO 0.06131393394849658f   // 1/sqrt(266)
#define NORMF 0.35355339059327373f   // 64^-0.25
#define DIAGF 0.0625f                // 0.5 * 64^-0.5
#define EPSF  1e-4f

typedef __attribute__((ext_vector_type(8))) short bf16x8;
typedef __attribute__((ext_vector_type(4))) float f32x4;

__device__ __forceinline__ unsigned fenc(float f) {
  unsigned u = __float_as_uint(f);
  return (u & 0x80000000u) ? ~u : (u | 0x80000000u);
}
__device__ __forceinline__ float fdec(unsigned u) {
  return (u & 0x80000000u) ? __uint_as_float(u & 0x7fffffffu) : __uint_as_float(~u);
}

__device__ __forceinline__ void split1(float x, unsigned short& h, unsigned short& l) {
  unsigned ux = __float_as_uint(x);
  float hf = __uint_as_float(ux & 0xffff0000u);
  h = (unsigned short)(ux >> 16);
  l = (unsigned short)(__float_as_uint(x - hf) >> 16);
}

__device__ __forceinline__ void splitf(float4 a, float4 b, bf16x8& hi, bf16x8& lo) {
  float x[8] = {a.x, a.y, a.z, a.w, b.x, b.y, b.z, b.w};
#pragma unroll
  for (int e = 0; e < 8; ++e) {
    unsigned short h, l;
    split1(x[e], h, l);
    hi[e] = (short)h;
    lo[e] = (short)l;
  }
}

// split-precision GEMM accumulate: acc += hh + hl + lh  (ll term ~2^-16, dropped)
__device__ __forceinline__ f32x4 mfma3(bf16x8 ah, bf16x8 al, bf16x8 bh, bf16x8 bl, f32x4 acc) {
  acc = __builtin_amdgcn_mfma_f32_16x16x32_bf16(ah, bh, acc, 0, 0, 0);
  acc = __builtin_amdgcn_mfma_f32_16x16x32_bf16(ah, bl, acc, 0, 0, 0);
  acc = __builtin_amdgcn_mfma_f32_16x16x32_bf16(al, bh, acc, 0, 0, 0);
  return acc;
}

// ---------------------------------------------------------------------------
// P prep: proj [266][64] f32 -> phi/plo [272][64] bf16 planes (rows >=266 zero)
// ---------------------------------------------------------------------------
__global__ __launch_bounds__(256) void pprep_kernel(const float* __restrict__ proj,
                                                    short* __restrict__ phi,
                                                    short* __restrict__ plo) {
  int idx = blockIdx.x * 256 + threadIdx.x;
  if (idx >= MPAD * DDIM) return;
  int j = idx >> 6;
  float x = (j < MDIM) ? proj[idx] : 0.f;
  unsigned short h, l;
  split1(x, h, l);
  phi[idx] = (short)h;
  plo[idx] = (short)l;
}

// ---------------------------------------------------------------------------
// Kernel A: global max of k_dash = NORMF*(K.P^T), MFMA bf16x3. 64 rows/block.
// ---------------------------------------------------------------------------
__global__ __launch_bounds__(256) void kmax_kernel(const float* __restrict__ k,
                                                   const short* __restrict__ phi,
                                                   const short* __restrict__ plo,
                                                   unsigned* __restrict__ kmax) {
  __shared__ float sK[64 * 76];
  const int tid = threadIdx.x;
  const int lane = tid & 63, wv = tid >> 6, lrow = lane & 15, lgrp = lane >> 4;
  const int bh = blockIdx.x >> 6, ch = blockIdx.x & 63;
  const float* kb = k + ((size_t)bh * NSEQ + (size_t)ch * 64) * DDIM;

#pragma unroll
  for (int t = 0; t < 4; ++t) {
    int fid = tid + t * 256, r = fid >> 4, d4 = fid & 15;
    *(float4*)&sK[r * 76 + d4 * 4] = ((const float4*)kb)[fid];
  }
  __syncthreads();

  bf16x8 ahi[2], alo[2];
#pragma unroll
  for (int s = 0; s < 2; ++s) {
    const float* p = &sK[(wv * 16 + lrow) * 76 + s * 32 + lgrp * 8];
    splitf(*(const float4*)p, *(const float4*)(p + 4), ahi[s], alo[s]);
  }

  float tmax = -1e30f;
#pragma unroll
  for (int jt = 0; jt < 17; ++jt) {
    f32x4 acc = {0.f, 0.f, 0.f, 0.f};
#pragma unroll
    for (int s = 0; s < 2; ++s) {
      const size_t bo = ((size_t)(jt * 16 + lrow)) * DDIM + s * 32 + lgrp * 8;
      acc = mfma3(ahi[s], alo[s], *(const bf16x8*)(phi + bo), *(const bf16x8*)(plo + bo), acc);
    }
    if (jt < 16 || lrow < 10) {
#pragma unroll
      for (int i = 0; i < 4; ++i) tmax = fmaxf(tmax, acc[i]);
    }
  }
  tmax *= NORMF;
#pragma unroll
  for (int off = 32; off; off >>= 1) tmax = fmaxf(tmax, __shfl_xor(tmax, off));
  if ((tid & 63) == 0) atomicMax(kmax, fenc(tmax));
}

// ---------------------------------------------------------------------------
// Kernel B (all-MFMA): dash -> exp -> k' bf16-split kT in LDS -> ctx-MFMA.
// 512 rows/block. Wave wv: dash for its 16 n-rows (all j); ctx for e-cols
// wv*16..+15 (all j). acc[17] f32x4 per wave.
// ---------------------------------------------------------------------------
__global__ __launch_bounds__(256, 2) void ctx_kernel(const float* __restrict__ k,
                                                     const float* __restrict__ v,
                                                     const short* __restrict__ phi,
                                                     const short* __restrict__ plo,
                                                     const unsigned* __restrict__ kmaxp,
                                                     float* __restrict__ ctx,
                                                     float* __restrict__ ksum) {
  __shared__ float sK[64 * 76];   // K tile; reused as kT bf16 hi/lo [64][72]
  __shared__ float sV[64 * 68];
  __shared__ float sDiag[64];
  unsigned short* kThi = (unsigned short*)sK;
  unsigned short* kTlo = kThi + 64 * 72;
  const int tid = threadIdx.x;
  const int lane = tid & 63, wv = tid >> 6, lrow = lane & 15, lgrp = lane >> 4;
  const int bh = blockIdx.x >> 3, c8 = blockIdx.x & 7;
  const float stab = fdec(*kmaxp);
  const float* kb = k + ((size_t)bh * NSEQ + (size_t)c8 * 512) * DDIM;
  const float* vb = v + ((size_t)bh * NSEQ + (size_t)c8 * 512) * DDIM;

  f32x4 acc[17];
#pragma unroll
  for (int jt = 0; jt < 17; ++jt) acc[jt] = (f32x4){0.f, 0.f, 0.f, 0.f};
  float ks[17];
#pragma unroll
  for (int jt = 0; jt < 17; ++jt) ks[jt] = 0.f;

  for (int rt = 0; rt < 8; ++rt) {
    // stage K,V f32 (prev chunk's trailing barrier guarantees buffers free)
#pragma unroll
    for (int t = 0; t < 4; ++t) {
      int fid = tid + t * 256, r = fid >> 4, d4 = fid & 15;
      *(float4*)&sK[r * 76 + d4 * 4] = ((const float4*)(kb + (size_t)rt * 64 * DDIM))[fid];
      *(float4*)&sV[r * 68 + d4 * 4] = ((const float4*)(vb + (size_t)rt * 64 * DDIM))[fid];
    }
    __syncthreads();   // B1
    if (tid < 64) {
      float s = 0.f;
      const float* row = &sK[tid * 76];
#pragma unroll
      for (int d = 0; d < 64; d += 4) {
        float4 x = *(const float4*)(row + d);
        s = fmaf(x.x, x.x, fmaf(x.y, x.y, fmaf(x.z, x.z, fmaf(x.w, x.w, s))));
      }
      sDiag[tid] = s * DIAGF;
    }
    // dash A-fragments (wave's own 16 rows)
    bf16x8 ahi[2], alo[2];
#pragma unroll
    for (int s = 0; s < 2; ++s) {
      const float* p = &sK[(wv * 16 + lrow) * 76 + s * 32 + lgrp * 8];
      splitf(*(const float4*)p, *(const float4*)(p + 4), ahi[s], alo[s]);
    }
    // V B-fragments (e-cols wv*16..+15), reused across all 5 chunks
    bf16x8 vbh[2], vbl[2];
#pragma unroll
    for (int ks2 = 0; ks2 < 2; ++ks2) {
      float tv[8];
#pragma unroll
      for (int e = 0; e < 8; ++e)
        tv[e] = sV[(ks2 * 32 + lgrp * 8 + e) * 68 + wv * 16 + lrow];
      splitf(make_float4(tv[0], tv[1], tv[2], tv[3]),
             make_float4(tv[4], tv[5], tv[6], tv[7]), vbh[ks2], vbl[ks2]);
    }
    __syncthreads();   // B2: sDiag ready; sK/sV fragment reads drained

#pragma unroll
    for (int c = 0; c < 5; ++c) {
      const int njt = (c < 4) ? 4 : 1;
#pragma unroll
      for (int t = 0; t < njt; ++t) {
        const int jt = c * 4 + t;
        f32x4 d = {0.f, 0.f, 0.f, 0.f};
#pragma unroll
        for (int s = 0; s < 2; ++s) {
          const size_t bo = ((size_t)(jt * 16 + lrow)) * DDIM + s * 32 + lgrp * 8;
          d = mfma3(ahi[s], alo[s], *(const bf16x8*)(phi + bo), *(const bf16x8*)(plo + bo), d);
        }
        const int jg = jt * 16 + lrow;
        ushort4 h4, l4;
        float kpsum = 0.f;
#pragma unroll
        for (int i = 0; i < 4; ++i) {
          const int nrow = wv * 16 + lgrp * 4 + i;
          float kd = d[i] * NORMF;
          float kp = (jg < MDIM) ? RATIO * (__expf(kd - sDiag[nrow] - stab) + EPSF) : 0.f;
          kpsum += kp;
          unsigned short h, l;
          split1(kp, h, l);
          ((unsigned short*)&h4)[i] = h;
          ((unsigned short*)&l4)[i] = l;
        }
        ks[jt] += kpsum;
        *(ushort4*)&kThi[(t * 16 + lrow) * 72 + wv * 16 + lgrp * 4] = h4;
        *(ushort4*)&kTlo[(t * 16 + lrow) * 72 + wv * 16 + lgrp * 4] = l4;
      }
      __syncthreads();   // B3: kT chunk ready
#pragma unroll
      for (int t = 0; t < njt; ++t) {
        const int jt = c * 4 + t;
#pragma unroll
        for (int ks2 = 0; ks2 < 2; ++ks2) {
          bf16x8 ah = *(const bf16x8*)&kThi[(t * 16 + lrow) * 72 + ks2 * 32 + lgrp * 8];
          bf16x8 al = *(const bf16x8*)&kTlo[(t * 16 + lrow) * 72 + ks2 * 32 + lgrp * 8];
          acc[jt] = mfma3(ah, al, vbh[ks2], vbl[ks2], acc[jt]);
        }
      }
      __syncthreads();   // B4: kT reads done (next chunk/rt may overwrite)
    }
  }

  // ksum: reduce wave-partials across lgrp, one atomic per (wave, j)
#pragma unroll
  for (int jt = 0; jt < 17; ++jt) {
    float s = ks[jt];
    s += __shfl_xor(s, 16);
    s += __shfl_xor(s, 32);
    const int jg = jt * 16 + lrow;
    if (lgrp == 0 && jg < MDIM) atomicAdd(&ksum[(size_t)bh * MDIM + jg], s);
  }
  // ctx: lane holds j = jt*16 + lgrp*4 + i, e = wv*16 + lrow
#pragma unroll
  for (int jt = 0; jt < 17; ++jt) {
#pragma unroll
    for (int i = 0; i < 4; ++i) {
      const int j = jt * 16 + lgrp * 4 + i;
      if (j < MDIM)
        atomicAdd(&ctx[((size_t)bh * MDIM + j) * DDIM + wv * 16 + lrow], acc[jt][i]);
    }
  }
}

// ---------------------------------------------------------------------------
// Kernel C (all-MFMA): q_dash MFMA -> in-register max/exp/Dinv -> q'' bf16
// split qT in LDS -> GEMM2 MFMA. 64 rows/block.
// ---------------------------------------------------------------------------
__global__ __launch_bounds__(256, 2) void out_kernel(const float* __restrict__ q,
                                                     const short* __restrict__ phi,
                                                     const short* __restrict__ plo,
                                                     const float* __restrict__ ctx,
                                                     const float* __restrict__ ksum,
                                                     float* __restrict__ out) {
  __shared__ float buf[64 * 76];   // Q tile; reused as qT bf16 hi/lo [64][72]
  __shared__ float sCtx[64 * 68];
  __shared__ float sDiag[64];
  __shared__ float sKs[MPAD];
  unsigned short* qThi = (unsigned short*)buf;
  unsigned short* qTlo = qThi + 64 * 72;
  const int tid = threadIdx.x;
  const int lane = tid & 63, wv = tid >> 6, lrow = lane & 15, lgrp = lane >> 4;
  const int bh = blockIdx.x >> 6, rc = blockIdx.x & 63;
  const float* qb = q + ((size_t)bh * NSEQ + (size_t)rc * 64) * DDIM;

#pragma unroll
  for (int t = 0; t < 4; ++t) {
    int fid = tid + t * 256, r = fid >> 4, d4 = fid & 15;
    *(float4*)&buf[r * 76 + d4 * 4] = ((const float4*)qb)[fid];
  }
  for (int t = tid; t < MPAD; t += 256) sKs[t] = (t < MDIM) ? ksum[(size_t)bh * MDIM + t] : 0.f;
  __syncthreads();
  if (tid < 64) {
    float s = 0.f;
    const float* row = &buf[tid * 76];
#pragma unroll
    for (int d = 0; d < 64; d += 4) {
      float4 x = *(const float4*)(row + d);
      s = fmaf(x.x, x.x, fmaf(x.y, x.y, fmaf(x.z, x.z, fmaf(x.w, x.w, s))));
    }
    sDiag[tid] = s * DIAGF;
  }
  bf16x8 ahi[2], alo[2];
#pragma unroll
  for (int s = 0; s < 2; ++s) {
    const float* p = &buf[(wv * 16 + lrow) * 76 + s * 32 + lgrp * 8];
    splitf(*(const float4*)p, *(const float4*)(p + 4), ahi[s], alo[s]);
  }
  __syncthreads();   // B2: sDiag ready, buf reads drained -> buf reusable

  f32x4 qd[17];
#pragma unroll
  for (int jt = 0; jt < 17; ++jt) {
    f32x4 a = {0.f, 0.f, 0.f, 0.f};
#pragma unroll
    for (int s = 0; s < 2; ++s) {
      const size_t bo = ((size_t)(jt * 16 + lrow)) * DDIM + s * 32 + lgrp * 8;
      a = mfma3(ahi[s], alo[s], *(const bf16x8*)(phi + bo), *(const bf16x8*)(plo + bo), a);
    }
#pragma unroll
    for (int i = 0; i < 4; ++i) qd[jt][i] = a[i] * NORMF;
  }

  // rows wv*16 + lgrp*4 + i; 16 lanes (lrow) share each row set
  float di[4];
#pragma unroll
  for (int i = 0; i < 4; ++i) {
    float m = -1e30f;
#pragma unroll
    for (int jt = 0; jt < 17; ++jt)
      if (jt < 16 || lrow < 10) m = fmaxf(m, qd[jt][i]);
    m = fmaxf(m, __shfl_xor(m, 1));
    m = fmaxf(m, __shfl_xor(m, 2));
    m = fmaxf(m, __shfl_xor(m, 4));
    m = fmaxf(m, __shfl_xor(m, 8));
    const float dg = sDiag[wv * 16 + lgrp * 4 + i];
    float s = 0.f;
#pragma unroll
    for (int jt = 0; jt < 17; ++jt) {
      const int jg = jt * 16 + lrow;
      float val = (jg < MDIM) ? RATIO * (__expf(qd[jt][i] - dg - m) + EPSF) : 0.f;
      qd[jt][i] = val;
      s = fmaf(val, sKs[jg], s);
    }
    s += __shfl_xor(s, 1);
    s += __shfl_xor(s, 2);
    s += __shfl_xor(s, 4);
    s += __shfl_xor(s, 8);
    di[i] = 1.0f / s;
  }

  f32x4 accO[4];
#pragma unroll
  for (int mt = 0; mt < 4; ++mt) accO[mt] = (f32x4){0.f, 0.f, 0.f, 0.f};

#pragma unroll
  for (int c = 0; c < 5; ++c) {
    const int nwr = (c < 4) ? 4 : 2;   // chunk 4: t=1 zero-fill (mask stale LDS)
    const int nks = (c < 4) ? 2 : 1;
    const int jn = (c < 4) ? 64 : 10;
#pragma unroll
    for (int t = 0; t < nwr; ++t) {
      const int jt = c * 4 + t;
#pragma unroll
      for (int i = 0; i < 4; ++i) {
        unsigned short h = 0, l = 0;
        if (jt < 17) split1(qd[jt][i] * di[i], h, l);
        qThi[(wv * 16 + lgrp * 4 + i) * 72 + t * 16 + lrow] = h;
        qTlo[(wv * 16 + lgrp * 4 + i) * 72 + t * 16 + lrow] = l;
      }
    }
#pragma unroll
    for (int t = 0; t < 4; ++t) {
      int fid = tid + t * 256, r = fid >> 4, e4 = fid & 15;
      if (r < jn)
        *(float4*)&sCtx[r * 68 + e4 * 4] =
            ((const float4*)(ctx + ((size_t)bh * MDIM + c * 64 + r) * DDIM))[e4];
    }
    __syncthreads();   // qT chunk + sCtx chunk ready
#pragma unroll
    for (int ks2 = 0; ks2 < nks; ++ks2) {
      float tv[8];
#pragma unroll
      for (int e = 0; e < 8; ++e)
        tv[e] = sCtx[(ks2 * 32 + lgrp * 8 + e) * 68 + wv * 16 + lrow];
      bf16x8 cbh, cbl;
      splitf(make_float4(tv[0], tv[1], tv[2], tv[3]),
             make_float4(tv[4], tv[5], tv[6], tv[7]), cbh, cbl);
#pragma unroll
      for (int mt = 0; mt < 4; ++mt) {
        bf16x8 ah = *(const bf16x8*)&qThi[(mt * 16 + lrow) * 72 + ks2 * 32 + lgrp * 8];
        bf16x8 al = *(const bf16x8*)&qTlo[(mt * 16 + lrow) * 72 + ks2 * 32 + lgrp * 8];
        accO[mt] = mfma3(ah, al, cbh, cbl, accO[mt]);
      }
    }
    __syncthreads();   // reads done before next chunk overwrites
  }

#pragma unroll
  for (int mt = 0; mt < 4; ++mt) {
#pragma unroll
    for (int i = 0; i < 4; ++i) {
      const int r = mt * 16 + lgrp * 4 + i;
      out[((size_t)bh * NSEQ + (size_t)rc * 64 + r) * DDIM + wv * 16 + lrow] = accO[mt][i];
    }
  }
}

extern "C" void kernel_launch(void* const* d_in, const int* in_sizes, int n_in,
                              void* d_out, int out_size, void* d_ws, size_t ws_size,
                              hipStream_t stream) {
  (void)in_sizes; (void)n_in; (void)out_size; (void)ws_size;
  const float* q = (const float*)d_in[0];
  const float* k = (const float*)d_in[1];
  const float* v = (const float*)d_in[2];
  const float* proj = (const float*)d_in[3];
  float* out = (float*)d_out;

  unsigned* kmax = (unsigned*)d_ws;
  float* ctx = (float*)((char*)d_ws + 256);
  float* ksum = ctx + (size_t)BH * MDIM * DDIM;
  short* phi = (short*)(ksum + (size_t)BH * MDIM);
  short* plo = phi + (size_t)MPAD * DDIM;
  const size_t zero_bytes = 256 + ((size_t)BH * MDIM * DDIM + (size_t)BH * MDIM) * 4;

  hipMemsetAsync(d_ws, 0, zero_bytes, stream);
  pprep_kernel<<<dim3((MPAD * DDIM + 255) / 256), dim3(256), 0, stream>>>(proj, phi, plo);
  kmax_kernel<<<dim3(BH * 64), dim3(256), 0, stream>>>(k, phi, plo, kmax);
  ctx_kernel<<<dim3(BH * 8), dim3(256), 0, stream>>>(k, v, phi, plo, kmax, ctx, ksum);
  out_kernel<<<dim3(BH * 64), dim3(256), 0, stream>>>(q, phi, plo, ctx, ksum, out);
}

// Round 5
// 473.032 us; speedup vs baseline: 2.2915x; 1.4631x over previous
//
#include <hip/hip_runtime.h>
#include <math.h>

#define BH    64
#define NSEQ  4096
#define DDIM  64
#define MDIM  266
#define MPAD  272
#define RATIO 0.06131393394849658f   // 1/sqrt(266)
#define NORMF 0.35355339059327373f   // 64^-0.25
#define DIAGF 0.0625f                // 0.5 * 64^-0.5
#define EPSF  1e-4f

typedef __attribute__((ext_vector_type(8))) short bf16x8;
typedef __attribute__((ext_vector_type(4))) float f32x4;

__device__ __forceinline__ unsigned fenc(float f) {
  unsigned u = __float_as_uint(f);
  return (u & 0x80000000u) ? ~u : (u | 0x80000000u);
}
__device__ __forceinline__ float fdec(unsigned u) {
  return (u & 0x80000000u) ? __uint_as_float(u & 0x7fffffffu) : __uint_as_float(~u);
}

__device__ __forceinline__ void split1(float x, unsigned short& h, unsigned short& l) {
  unsigned ux = __float_as_uint(x);
  float hf = __uint_as_float(ux & 0xffff0000u);
  h = (unsigned short)(ux >> 16);
  l = (unsigned short)(__float_as_uint(x - hf) >> 16);
}

__device__ __forceinline__ void splitf(float4 a, float4 b, bf16x8& hi, bf16x8& lo) {
  float x[8] = {a.x, a.y, a.z, a.w, b.x, b.y, b.z, b.w};
#pragma unroll
  for (int e = 0; e < 8; ++e) {
    unsigned short h, l;
    split1(x[e], h, l);
    hi[e] = (short)h;
    lo[e] = (short)l;
  }
}

// split-precision GEMM accumulate: acc += hh + hl + lh  (ll term ~2^-16, dropped)
__device__ __forceinline__ f32x4 mfma3(bf16x8 ah, bf16x8 al, bf16x8 bh, bf16x8 bl, f32x4 acc) {
  acc = __builtin_amdgcn_mfma_f32_16x16x32_bf16(ah, bh, acc, 0, 0, 0);
  acc = __builtin_amdgcn_mfma_f32_16x16x32_bf16(ah, bl, acc, 0, 0, 0);
  acc = __builtin_amdgcn_mfma_f32_16x16x32_bf16(al, bh, acc, 0, 0, 0);
  return acc;
}

// ---------------------------------------------------------------------------
// P prep: proj [266][64] f32 -> phi/plo [272][64] bf16 planes (rows >=266 zero)
// ---------------------------------------------------------------------------
__global__ __launch_bounds__(256) void pprep_kernel(const float* __restrict__ proj,
                                                    short* __restrict__ phi,
                                                    short* __restrict__ plo) {
  int idx = blockIdx.x * 256 + threadIdx.x;
  if (idx >= MPAD * DDIM) return;
  int j = idx >> 6;
  float x = (j < MDIM) ? proj[idx] : 0.f;
  unsigned short h, l;
  split1(x, h, l);
  phi[idx] = (short)h;
  plo[idx] = (short)l;
}

// ---------------------------------------------------------------------------
// Kernel A: global max of k_dash = NORMF*(K.P^T), MFMA bf16x3.
// 512 blocks x 8 chunks of 64 rows; ONE atomic per block (was 16K same-line
// atomics -> 276us drain stall).
// ---------------------------------------------------------------------------
__global__ __launch_bounds__(256) void kmax_kernel(const float* __restrict__ k,
                                                   const short* __restrict__ phi,
                                                   const short* __restrict__ plo,
                                                   unsigned* __restrict__ kmax) {
  __shared__ float sK[64 * 76];
  __shared__ float wmax[4];
  const int tid = threadIdx.x;
  const int lane = tid & 63, wv = tid >> 6, lrow = lane & 15, lgrp = lane >> 4;

  float tmax = -1e30f;
  for (int it = 0; it < 8; ++it) {
    const int chunk = blockIdx.x * 8 + it;   // 0..4095
    const int bh = chunk >> 6, ch = chunk & 63;
    const float* kb = k + ((size_t)bh * NSEQ + (size_t)ch * 64) * DDIM;
    __syncthreads();   // prev iteration's fragment reads of sK done
#pragma unroll
    for (int t = 0; t < 4; ++t) {
      int fid = tid + t * 256, r = fid >> 4, d4 = fid & 15;
      *(float4*)&sK[r * 76 + d4 * 4] = ((const float4*)kb)[fid];
    }
    __syncthreads();

    bf16x8 ahi[2], alo[2];
#pragma unroll
    for (int s = 0; s < 2; ++s) {
      const float* p = &sK[(wv * 16 + lrow) * 76 + s * 32 + lgrp * 8];
      splitf(*(const float4*)p, *(const float4*)(p + 4), ahi[s], alo[s]);
    }

#pragma unroll
    for (int jt = 0; jt < 17; ++jt) {
      f32x4 acc = {0.f, 0.f, 0.f, 0.f};
#pragma unroll
      for (int s = 0; s < 2; ++s) {
        const size_t bo = ((size_t)(jt * 16 + lrow)) * DDIM + s * 32 + lgrp * 8;
        acc = mfma3(ahi[s], alo[s], *(const bf16x8*)(phi + bo), *(const bf16x8*)(plo + bo), acc);
      }
      if (jt < 16 || lrow < 10) {
#pragma unroll
        for (int i = 0; i < 4; ++i) tmax = fmaxf(tmax, acc[i]);
      }
    }
  }
#pragma unroll
  for (int off = 32; off; off >>= 1) tmax = fmaxf(tmax, __shfl_xor(tmax, off));
  if (lane == 0) wmax[wv] = tmax;
  __syncthreads();
  if (tid == 0) {
    float m = fmaxf(fmaxf(wmax[0], wmax[1]), fmaxf(wmax[2], wmax[3]));
    atomicMax(kmax, fenc(m * NORMF));
  }
}

// ---------------------------------------------------------------------------
// Kernel B (all-MFMA): dash -> exp -> k' bf16-split kT in LDS -> ctx-MFMA.
// 512 rows/block. Wave wv: dash for its 16 n-rows (all j); ctx for e-cols
// wv*16..+15 (all j). acc[17] f32x4 per wave.
// ---------------------------------------------------------------------------
__global__ __launch_bounds__(256, 2) void ctx_kernel(const float* __restrict__ k,
                                                     const float* __restrict__ v,
                                                     const short* __restrict__ phi,
                                                     const short* __restrict__ plo,
                                                     const unsigned* __restrict__ kmaxp,
                                                     float* __restrict__ ctx,
                                                     float* __restrict__ ksum) {
  __shared__ float sK[64 * 76];   // K tile; reused as kT bf16 hi/lo [64][72]
  __shared__ float sV[64 * 68];
  __shared__ float sDiag[64];
  unsigned short* kThi = (unsigned short*)sK;
  unsigned short* kTlo = kThi + 64 * 72;
  const int tid = threadIdx.x;
  const int lane = tid & 63, wv = tid >> 6, lrow = lane & 15, lgrp = lane >> 4;
  const int bh = blockIdx.x >> 3, c8 = blockIdx.x & 7;
  const float stab = fdec(*kmaxp);
  const float* kb = k + ((size_t)bh * NSEQ + (size_t)c8 * 512) * DDIM;
  const float* vb = v + ((size_t)bh * NSEQ + (size_t)c8 * 512) * DDIM;

  f32x4 acc[17];
#pragma unroll
  for (int jt = 0; jt < 17; ++jt) acc[jt] = (f32x4){0.f, 0.f, 0.f, 0.f};
  float ks[17];
#pragma unroll
  for (int jt = 0; jt < 17; ++jt) ks[jt] = 0.f;

  for (int rt = 0; rt < 8; ++rt) {
    // stage K,V f32 (prev chunk's trailing barrier guarantees buffers free)
#pragma unroll
    for (int t = 0; t < 4; ++t) {
      int fid = tid + t * 256, r = fid >> 4, d4 = fid & 15;
      *(float4*)&sK[r * 76 + d4 * 4] = ((const float4*)(kb + (size_t)rt * 64 * DDIM))[fid];
      *(float4*)&sV[r * 68 + d4 * 4] = ((const float4*)(vb + (size_t)rt * 64 * DDIM))[fid];
    }
    __syncthreads();   // B1
    if (tid < 64) {
      float s = 0.f;
      const float* row = &sK[tid * 76];
#pragma unroll
      for (int d = 0; d < 64; d += 4) {
        float4 x = *(const float4*)(row + d);
        s = fmaf(x.x, x.x, fmaf(x.y, x.y, fmaf(x.z, x.z, fmaf(x.w, x.w, s))));
      }
      sDiag[tid] = s * DIAGF;
    }
    // dash A-fragments (wave's own 16 rows)
    bf16x8 ahi[2], alo[2];
#pragma unroll
    for (int s = 0; s < 2; ++s) {
      const float* p = &sK[(wv * 16 + lrow) * 76 + s * 32 + lgrp * 8];
      splitf(*(const float4*)p, *(const float4*)(p + 4), ahi[s], alo[s]);
    }
    // V B-fragments (e-cols wv*16..+15), reused across all 5 chunks
    bf16x8 vbh[2], vbl[2];
#pragma unroll
    for (int ks2 = 0; ks2 < 2; ++ks2) {
      float tv[8];
#pragma unroll
      for (int e = 0; e < 8; ++e)
        tv[e] = sV[(ks2 * 32 + lgrp * 8 + e) * 68 + wv * 16 + lrow];
      splitf(make_float4(tv[0], tv[1], tv[2], tv[3]),
             make_float4(tv[4], tv[5], tv[6], tv[7]), vbh[ks2], vbl[ks2]);
    }
    __syncthreads();   // B2: sDiag ready; sK/sV fragment reads drained

#pragma unroll
    for (int c = 0; c < 5; ++c) {
      const int njt = (c < 4) ? 4 : 1;
#pragma unroll
      for (int t = 0; t < njt; ++t) {
        const int jt = c * 4 + t;
        f32x4 d = {0.f, 0.f, 0.f, 0.f};
#pragma unroll
        for (int s = 0; s < 2; ++s) {
          const size_t bo = ((size_t)(jt * 16 + lrow)) * DDIM + s * 32 + lgrp * 8;
          d = mfma3(ahi[s], alo[s], *(const bf16x8*)(phi + bo), *(const bf16x8*)(plo + bo), d);
        }
        const int jg = jt * 16 + lrow;
        ushort4 h4, l4;
        float kpsum = 0.f;
#pragma unroll
        for (int i = 0; i < 4; ++i) {
          const int nrow = wv * 16 + lgrp * 4 + i;
          float kd = d[i] * NORMF;
          float kp = (jg < MDIM) ? RATIO * (__expf(kd - sDiag[nrow] - stab) + EPSF) : 0.f;
          kpsum += kp;
          unsigned short h, l;
          split1(kp, h, l);
          ((unsigned short*)&h4)[i] = h;
          ((unsigned short*)&l4)[i] = l;
        }
        ks[jt] += kpsum;
        *(ushort4*)&kThi[(t * 16 + lrow) * 72 + wv * 16 + lgrp * 4] = h4;
        *(ushort4*)&kTlo[(t * 16 + lrow) * 72 + wv * 16 + lgrp * 4] = l4;
      }
      __syncthreads();   // B3: kT chunk ready
#pragma unroll
      for (int t = 0; t < njt; ++t) {
        const int jt = c * 4 + t;
#pragma unroll
        for (int ks2 = 0; ks2 < 2; ++ks2) {
          bf16x8 ah = *(const bf16x8*)&kThi[(t * 16 + lrow) * 72 + ks2 * 32 + lgrp * 8];
          bf16x8 al = *(const bf16x8*)&kTlo[(t * 16 + lrow) * 72 + ks2 * 32 + lgrp * 8];
          acc[jt] = mfma3(ah, al, vbh[ks2], vbl[ks2], acc[jt]);
        }
      }
      __syncthreads();   // B4: kT reads done (next chunk/rt may overwrite)
    }
  }

  // ksum: reduce wave-partials across lgrp, one atomic per (wave, j)
#pragma unroll
  for (int jt = 0; jt < 17; ++jt) {
    float s = ks[jt];
    s += __shfl_xor(s, 16);
    s += __shfl_xor(s, 32);
    const int jg = jt * 16 + lrow;
    if (lgrp == 0 && jg < MDIM) atomicAdd(&ksum[(size_t)bh * MDIM + jg], s);
  }
  // ctx: lane holds j = jt*16 + lgrp*4 + i, e = wv*16 + lrow
#pragma unroll
  for (int jt = 0; jt < 17; ++jt) {
#pragma unroll
    for (int i = 0; i < 4; ++i) {
      const int j = jt * 16 + lgrp * 4 + i;
      if (j < MDIM)
        atomicAdd(&ctx[((size_t)bh * MDIM + j) * DDIM + wv * 16 + lrow], acc[jt][i]);
    }
  }
}

// ---------------------------------------------------------------------------
// Kernel C (all-MFMA): q_dash MFMA -> in-register max/exp/Dinv -> q'' bf16
// split qT in LDS -> GEMM2 MFMA. 64 rows/block.
// ---------------------------------------------------------------------------
__global__ __launch_bounds__(256, 2) void out_kernel(const float* __restrict__ q,
                                                     const short* __restrict__ phi,
                                                     const short* __restrict__ plo,
                                                     const float* __restrict__ ctx,
                                                     const float* __restrict__ ksum,
                                                     float* __restrict__ out) {
  __shared__ float buf[64 * 76];   // Q tile; reused as qT bf16 hi/lo [64][72]
  __shared__ float sCtx[64 * 68];
  __shared__ float sDiag[64];
  __shared__ float sKs[MPAD];
  unsigned short* qThi = (unsigned short*)buf;
  unsigned short* qTlo = qThi + 64 * 72;
  const int tid = threadIdx.x;
  const int lane = tid & 63, wv = tid >> 6, lrow = lane & 15, lgrp = lane >> 4;
  const int bh = blockIdx.x >> 6, rc = blockIdx.x & 63;
  const float* qb = q + ((size_t)bh * NSEQ + (size_t)rc * 64) * DDIM;

#pragma unroll
  for (int t = 0; t < 4; ++t) {
    int fid = tid + t * 256, r = fid >> 4, d4 = fid & 15;
    *(float4*)&buf[r * 76 + d4 * 4] = ((const float4*)qb)[fid];
  }
  for (int t = tid; t < MPAD; t += 256) sKs[t] = (t < MDIM) ? ksum[(size_t)bh * MDIM + t] : 0.f;
  __syncthreads();
  if (tid < 64) {
    float s = 0.f;
    const float* row = &buf[tid * 76];
#pragma unroll
    for (int d = 0; d < 64; d += 4) {
      float4 x = *(const float4*)(row + d);
      s = fmaf(x.x, x.x, fmaf(x.y, x.y, fmaf(x.z, x.z, fmaf(x.w, x.w, s))));
    }
    sDiag[tid] = s * DIAGF;
  }
  bf16x8 ahi[2], alo[2];
#pragma unroll
  for (int s = 0; s < 2; ++s) {
    const float* p = &buf[(wv * 16 + lrow) * 76 + s * 32 + lgrp * 8];
    splitf(*(const float4*)p, *(const float4*)(p + 4), ahi[s], alo[s]);
  }
  __syncthreads();   // B2: sDiag ready, buf reads drained -> buf reusable

  f32x4 qd[17];
#pragma unroll
  for (int jt = 0; jt < 17; ++jt) {
    f32x4 a = {0.f, 0.f, 0.f, 0.f};
#pragma unroll
    for (int s = 0; s < 2; ++s) {
      const size_t bo = ((size_t)(jt * 16 + lrow)) * DDIM + s * 32 + lgrp * 8;
      a = mfma3(ahi[s], alo[s], *(const bf16x8*)(phi + bo), *(const bf16x8*)(plo + bo), a);
    }
#pragma unroll
    for (int i = 0; i < 4; ++i) qd[jt][i] = a[i] * NORMF;
  }

  // rows wv*16 + lgrp*4 + i; 16 lanes (lrow) share each row set
  float di[4];
#pragma unroll
  for (int i = 0; i < 4; ++i) {
    float m = -1e30f;
#pragma unroll
    for (int jt = 0; jt < 17; ++jt)
      if (jt < 16 || lrow < 10) m = fmaxf(m, qd[jt][i]);
    m = fmaxf(m, __shfl_xor(m, 1));
    m = fmaxf(m, __shfl_xor(m, 2));
    m = fmaxf(m, __shfl_xor(m, 4));
    m = fmaxf(m, __shfl_xor(m, 8));
    const float dg = sDiag[wv * 16 + lgrp * 4 + i];
    float s = 0.f;
#pragma unroll
    for (int jt = 0; jt < 17; ++jt) {
      const int jg = jt * 16 + lrow;
      float val = (jg < MDIM) ? RATIO * (__expf(qd[jt][i] - dg - m) + EPSF) : 0.f;
      qd[jt][i] = val;
      s = fmaf(val, sKs[jg], s);
    }
    s += __shfl_xor(s, 1);
    s += __shfl_xor(s, 2);
    s += __shfl_xor(s, 4);
    s += __shfl_xor(s, 8);
    di[i] = 1.0f / s;
  }

  f32x4 accO[4];
#pragma unroll
  for (int mt = 0; mt < 4; ++mt) accO[mt] = (f32x4){0.f, 0.f, 0.f, 0.f};

#pragma unroll
  for (int c = 0; c < 5; ++c) {
    const int nwr = (c < 4) ? 4 : 2;   // chunk 4: t=1 zero-fill (mask stale LDS)
    const int nks = (c < 4) ? 2 : 1;
    const int jn = (c < 4) ? 64 : 10;
#pragma unroll
    for (int t = 0; t < nwr; ++t) {
      const int jt = c * 4 + t;
#pragma unroll
      for (int i = 0; i < 4; ++i) {
        unsigned short h = 0, l = 0;
        if (jt < 17) split1(qd[jt][i] * di[i], h, l);
        qThi[(wv * 16 + lgrp * 4 + i) * 72 + t * 16 + lrow] = h;
        qTlo[(wv * 16 + lgrp * 4 + i) * 72 + t * 16 + lrow] = l;
      }
    }
#pragma unroll
    for (int t = 0; t < 4; ++t) {
      int fid = tid + t * 256, r = fid >> 4, e4 = fid & 15;
      if (r < jn)
        *(float4*)&sCtx[r * 68 + e4 * 4] =
            ((const float4*)(ctx + ((size_t)bh * MDIM + c * 64 + r) * DDIM))[e4];
    }
    __syncthreads();   // qT chunk + sCtx chunk ready
#pragma unroll
    for (int ks2 = 0; ks2 < nks; ++ks2) {
      float tv[8];
#pragma unroll
      for (int e = 0; e < 8; ++e)
        tv[e] = sCtx[(ks2 * 32 + lgrp * 8 + e) * 68 + wv * 16 + lrow];
      bf16x8 cbh, cbl;
      splitf(make_float4(tv[0], tv[1], tv[2], tv[3]),
             make_float4(tv[4], tv[5], tv[6], tv[7]), cbh, cbl);
#pragma unroll
      for (int mt = 0; mt < 4; ++mt) {
        bf16x8 ah = *(const bf16x8*)&qThi[(mt * 16 + lrow) * 72 + ks2 * 32 + lgrp * 8];
        bf16x8 al = *(const bf16x8*)&qTlo[(mt * 16 + lrow) * 72 + ks2 * 32 + lgrp * 8];
        accO[mt] = mfma3(ah, al, cbh, cbl, accO[mt]);
      }
    }
    __syncthreads();   // reads done before next chunk overwrites
  }

#pragma unroll
  for (int mt = 0; mt < 4; ++mt) {
#pragma unroll
    for (int i = 0; i < 4; ++i) {
      const int r = mt * 16 + lgrp * 4 + i;
      out[((size_t)bh * NSEQ + (size_t)rc * 64 + r) * DDIM + wv * 16 + lrow] = accO[mt][i];
    }
  }
}

extern "C" void kernel_launch(void* const* d_in, const int* in_sizes, int n_in,
                              void* d_out, int out_size, void* d_ws, size_t ws_size,
                              hipStream_t stream) {
  (void)in_sizes; (void)n_in; (void)out_size; (void)ws_size;
  const float* q = (const float*)d_in[0];
  const float* k = (const float*)d_in[1];
  const float* v = (const float*)d_in[2];
  const float* proj = (const float*)d_in[3];
  float* out = (float*)d_out;

  unsigned* kmax = (unsigned*)d_ws;
  float* ctx = (float*)((char*)d_ws + 256);
  float* ksum = ctx + (size_t)BH * MDIM * DDIM;
  short* phi = (short*)(ksum + (size_t)BH * MDIM);
  short* plo = phi + (size_t)MPAD * DDIM;
  const size_t zero_bytes = 256 + ((size_t)BH * MDIM * DDIM + (size_t)BH * MDIM) * 4;

  hipMemsetAsync(d_ws, 0, zero_bytes, stream);
  pprep_kernel<<<dim3((MPAD * DDIM + 255) / 256), dim3(256), 0, stream>>>(proj, phi, plo);
  kmax_kernel<<<dim3(512), dim3(256), 0, stream>>>(k, phi, plo, kmax);
  ctx_kernel<<<dim3(BH * 8), dim3(256), 0, stream>>>(k, v, phi, plo, kmax, ctx, ksum);
  out_kernel<<<dim3(BH * 64), dim3(256), 0, stream>>>(q, phi, plo, ctx, ksum, out);
}